// Round 3
// baseline (307.065 us; speedup 1.0000x reference)
//
#include <hip/hip_runtime.h>
#include <hip/hip_bf16.h>

#define BATCH 16384
#define HID   1024
#define EMBD  512
#define NOPS  8
#define MAXT  136   // max tile slots: sum ceil(cnt_e/128) <= 135
#define CNTS  16    // cnt stride in ints (64 B) — one cache line per expert

typedef __attribute__((ext_vector_type(8))) short bf16x8;
typedef __attribute__((ext_vector_type(4))) float f32x4;

__device__ __forceinline__ unsigned short f2bf(float f) {
  unsigned int u = __float_as_uint(f);
  u += 0x7FFF + ((u >> 16) & 1);
  return (unsigned short)(u >> 16);
}

__device__ __forceinline__ unsigned int pk2(float a, float b) {
  __hip_bfloat162 t = __float22bfloat162_rn(make_float2(a, b));
  return *(unsigned int*)(&t);
}

__device__ __forceinline__ void lds_load16(void* lds, const void* g) {
  __builtin_amdgcn_global_load_lds(
      (const __attribute__((address_space(1))) unsigned int*)g,
      (__attribute__((address_space(3))) unsigned int*)lds, 16, 0, 0);
}

// XCD-locality decode: linear blocks round-robin across 8 XCDs, so bid&7 is
// the XCD. All 8 nx-blocks of a g land on one XCD (A-slab L2 reuse), and each
// XCD covers contiguous g-range [17c, 17c+17) ~= one expert (W-slab in L2).
__device__ __forceinline__ void decode_bid(int bid, int& g, int& nx) {
  g = 17 * (bid & 7) + (bid >> 6);
  nx = (bid >> 3) & 7;
}

// LDS-free weight transpose tile, fq-major slab layout:
//   slab[kq][n][kk] bf16 (kq=k/8 in 0..3, n in 0..127, kk=k%8)
//   value = W[ks*32 + kq*8 + kk][nx*128 + n]
// Fragment ds_read (fq*128+row)*16B hits each bank-quad twice per wave
// (2-way = free, m136) -> conflict-free fragment reads.
__device__ __forceinline__ void w_prep_tile(const float* __restrict__ W,
                                            short* __restrict__ Wp,
                                            int ks, int nx, int tid) {
  int n = tid & 127, kh = tid >> 7;           // kh: low/high 16 of the 32-k tile
  const float* src = W + (size_t)(ks * 32 + kh * 16) * 1024 + nx * 128 + n;
  float v[16];
#pragma unroll
  for (int kk = 0; kk < 16; ++kk) v[kk] = src[(size_t)kk * 1024];
  uint4 a, b;
  a.x = pk2(v[0], v[1]);  a.y = pk2(v[2], v[3]);
  a.z = pk2(v[4], v[5]);  a.w = pk2(v[6], v[7]);
  b.x = pk2(v[8], v[9]);  b.y = pk2(v[10], v[11]);
  b.z = pk2(v[12], v[13]); b.w = pk2(v[14], v[15]);
  uint4* dst = (uint4*)Wp;
  dst[(2 * kh) * 128 + n]     = a;            // kq = 2*kh   (k 0..7 of this half)
  dst[(2 * kh + 1) * 128 + n] = b;            // kq = 2*kh+1 (k 8..15)
}

// ---- phase 0: bucket (64) + ce (128) + W1 prep (2048) + xb convert (4096) ---
// xb = bf16(x) in token order — bucket-independent, so it rides in phase 0.
// gemm1 then gathers A rows straight from xb via per-lane global_load_lds
// (no Ap slab, no prep kernel, no VALU repack on the gemm critical path).
// ce[e][n] = b1[e][n] + sum_k emb[e][k] * W1[e][1024+k][n] — embedding half of
// GEMM1 collapses to a per-(expert,n) constant, cutting GEMM1 K 1536 -> 1024.
__global__ void bucket_ce_k(const int* __restrict__ ops, int* __restrict__ cnt,
                            int* __restrict__ idx, const float* __restrict__ W1,
                            const float* __restrict__ emb,
                            const float* __restrict__ b1, float* __restrict__ ce,
                            short* __restrict__ W1p, const float* __restrict__ x,
                            unsigned int* __restrict__ xb) {
  int bid = blockIdx.x;
  int tid = threadIdx.x;
  if (bid >= 2240) {
    // ---- xb path: f32 -> bf16, 4096 blocks * 4096 elems ----
    size_t i = ((size_t)(bid - 2240) * 256 + tid) * 16;
    const float4* src = (const float4*)(x + i);
    float4 f0 = src[0], f1 = src[1], f2v = src[2], f3 = src[3];
    uint4 p0 = make_uint4(pk2(f0.x, f0.y), pk2(f0.z, f0.w),
                          pk2(f1.x, f1.y), pk2(f1.z, f1.w));
    uint4 p1 = make_uint4(pk2(f2v.x, f2v.y), pk2(f2v.z, f2v.w),
                          pk2(f3.x, f3.y), pk2(f3.z, f3.w));
    uint4* dst = (uint4*)(xb + i / 2);
    dst[0] = p0;
    dst[1] = p1;
    return;
  }
  if (bid >= 192) {
    // ---- W1 path: 8 e * 8 nx * 32 ks (first 1024 rows only) ----
    int b = bid - 192;
    int e = b / 256; int rr = b % 256; int nx = rr / 32, ks = rr % 32;
    w_prep_tile(W1 + (size_t)e * 1536 * 1024,
                W1p + ((size_t)(e * 8 + nx) * 32 + ks) * 4096, ks, nx, tid);
    return;
  }
  if (bid >= 64) {
    // ---- ce path ----
    int cb = bid - 64;
    int e = cb >> 4, kp = cb & 15;
    int n = tid * 4;
    const float* Wc = W1 + (size_t)e * 1536 * 1024 + (size_t)(1024 + kp * 32) * 1024 + n;
    const float* ee = emb + e * EMBD + kp * 32;
    float4 a = make_float4(0.f, 0.f, 0.f, 0.f);
#pragma unroll
    for (int kk = 0; kk < 32; ++kk) {
      float s = ee[kk];
      float4 r = *(const float4*)(Wc + (size_t)kk * 1024);
      a.x += s * r.x; a.y += s * r.y; a.z += s * r.z; a.w += s * r.w;
    }
    if (kp == 0) {
      float4 b = *(const float4*)(b1 + e * HID + n);
      a.x += b.x; a.y += b.y; a.z += b.z; a.w += b.w;
    }
    float* d = ce + e * HID + n;
    atomicAdd(d + 0, a.x); atomicAdd(d + 1, a.y);
    atomicAdd(d + 2, a.z); atomicAdd(d + 3, a.w);
    return;
  }
  // ---- bucket path (block-aggregated atomics) ----
  __shared__ int wcnt[4][NOPS];
  __shared__ int wbase[4][NOPS];
  int lane = tid & 63, w = tid >> 6;
  int t = bid * 256 + tid;
  int op = ops[t];
  unsigned long long msave = 0;
#pragma unroll
  for (int o = 0; o < NOPS; ++o) {
    unsigned long long mm = __ballot(op == o);
    if (op == o) msave = mm;
    if (lane == o) wcnt[w][o] = __popcll(mm);
  }
  __syncthreads();
  if (tid < NOPS) {
    int c0 = wcnt[0][tid], c1 = wcnt[1][tid], c2 = wcnt[2][tid], c3 = wcnt[3][tid];
    int base = atomicAdd(&cnt[tid * CNTS], c0 + c1 + c2 + c3);
    wbase[0][tid] = base;
    wbase[1][tid] = base + c0;
    wbase[2][tid] = base + c0 + c1;
    wbase[3][tid] = base + c0 + c1 + c2;
  }
  __syncthreads();
  int pre = __popcll(msave & ((1ull << lane) - 1ull));
  idx[op * BATCH + wbase[w][op] + pre] = t;
}

// build tile descriptors + pad index lists to tile multiples (parallel fill)
__global__ void schedule_k(const int* __restrict__ cnt, int* __restrict__ desc,
                           int* __restrict__ ntp, int* __restrict__ idx) {
  __shared__ int base[NOPS + 1];
  int tid = threadIdx.x;
  if (tid == 0) {
    int n = 0;
    for (int e = 0; e < NOPS; ++e) { base[e] = n; n += (cnt[e * CNTS] + 127) >> 7; }
    base[NOPS] = n;
    *ntp = n;
  }
  __syncthreads();
  for (int e = 0; e < NOPS; ++e) {
    int b0 = base[e], nt = base[e + 1] - b0;
    for (int t = tid; t < nt; t += 256) {
      desc[2 * (b0 + t)] = e;
      desc[2 * (b0 + t) + 1] = t * 128;
    }
  }
  for (int e = 0; e < NOPS; ++e) {
    int c = cnt[e * CNTS];
    int cp = (c + 127) & ~127;
    for (int p = c + tid; p < cp; p += 256) idx[e * BATCH + p] = 0;
  }
}

// ---------------- phase 1: GEMM1 gathered-DMA A (1088) + W2 prep (2048) ------
// h = relu(x_tile @ W1[e][:1024] + ce[e]); K = 1024 (32 iters).
// 2-phase double-buffered schedule (T3-min): STAGE(ks+1) issued BEFORE the
// MFMA work on ks; ONE s_waitcnt vmcnt(0)+s_barrier per iter at the END, so
// DMA latency hides under ds_read+MFMA (old code barriered right after issue:
// full L2 latency on the critical path every K-step -> MfmaUtil 18%).
// Safety: each wave's ds_reads retire before its barrier (their data feeds
// MFMAs preceding the asm; "memory" clobber pins LDS op order), so the buffer
// overwritten by iter t+1's STAGE was fully consumed before iter t's barrier.
__global__ __launch_bounds__(256) void gemm1_w2_k(
    const unsigned int* __restrict__ xb, const int* __restrict__ idx,
    const float* __restrict__ ce, const short* __restrict__ W1p,
    unsigned short* __restrict__ hp, const int* __restrict__ desc,
    const int* __restrict__ ntp, const float* __restrict__ W2,
    short* __restrict__ W2p) {
  int bid = blockIdx.x;
  int tid = threadIdx.x;
  if (bid >= 8 * MAXT) {
    // ---- W2 path: 8 e * 8 nx * 32 ks ----
    int b = bid - 8 * MAXT;
    int e = b / 256; int rr = b % 256; int nx = rr / 32, ks = rr % 32;
    w_prep_tile(W2 + (size_t)e * 1024 * 1024,
                W2p + ((size_t)(e * 8 + nx) * 32 + ks) * 4096, ks, nx, tid);
    return;
  }
  int g, nx;
  decode_bid(bid, g, nx);
  if (g >= *ntp) return;
  int e = desc[2 * g], rs = desc[2 * g + 1];

  __shared__ __align__(16) char smem[32768];   // 2 x (8KB A + 8KB B)

  int lane = tid & 63, w = tid >> 6;
  int wm = w >> 1, wn = w & 1;
  int fr = lane & 15, fq = lane >> 4;

  // gathered A sources: lane i of wave w stages rows lane / 64+lane, kq=w
  int t0 = idx[e * BATCH + rs + lane];
  int t1 = idx[e * BATCH + rs + 64 + lane];
  const char* a0 = (const char*)xb + (size_t)t0 * 2048 + w * 16;
  const char* a1 = (const char*)xb + (size_t)t1 * 2048 + w * 16;
  const char* Bsrc = (const char*)W1p + (size_t)(e * 8 + nx) * 32 * 8192;

  // prologue: stage buf0 (ks=0), drain, sync
  lds_load16(smem + w * 2048,         a0);
  lds_load16(smem + w * 2048 + 1024,  a1);
  lds_load16(smem + 8192 + w * 1024,  Bsrc + w * 1024 + lane * 16);
  lds_load16(smem + 12288 + w * 1024, Bsrc + 4096 + w * 1024 + lane * 16);
  asm volatile("s_waitcnt vmcnt(0)" ::: "memory");
  __builtin_amdgcn_s_barrier();

  f32x4 acc[4][4] = {};

  for (int ks = 0; ks < 32; ++ks) {
    int cur = ks & 1;
    char* nb = smem + (cur ^ 1) * 16384;
    if (ks < 31) {   // issue next-tile staging; latency overlaps this tile's MFMA
      const char* bs = Bsrc + (ks + 1) * 8192;
      lds_load16(nb + w * 2048,         a0 + (ks + 1) * 64);
      lds_load16(nb + w * 2048 + 1024,  a1 + (ks + 1) * 64);
      lds_load16(nb + 8192 + w * 1024,  bs + w * 1024 + lane * 16);
      lds_load16(nb + 12288 + w * 1024, bs + 4096 + w * 1024 + lane * 16);
    }
    const short* lA = (const short*)(smem + cur * 16384);
    const short* lB = (const short*)(smem + cur * 16384 + 8192);
    bf16x8 af[4], bfr[4];
#pragma unroll
    for (int i = 0; i < 4; ++i)
      af[i] = *(const bf16x8*)&lA[(fq * 128 + wm * 64 + i * 16 + fr) * 8];
#pragma unroll
    for (int j = 0; j < 4; ++j)
      bfr[j] = *(const bf16x8*)&lB[(fq * 128 + wn * 64 + j * 16 + fr) * 8];
#pragma unroll
    for (int i = 0; i < 4; ++i)
#pragma unroll
      for (int j = 0; j < 4; ++j)
        acc[i][j] = __builtin_amdgcn_mfma_f32_16x16x32_bf16(af[i], bfr[j], acc[i][j], 0, 0, 0);
    asm volatile("s_waitcnt vmcnt(0)" ::: "memory");
    __builtin_amdgcn_s_barrier();
  }

  // epilogue: +ce (bias incl. embedding term) + relu + bf16, coalesced via LDS.
  // hp layout (fq-major): [g][ks2(32)][kq(4)][128 r][8 k] — gemm2 staging is a
  // linear 8 KB slab copy. LDS round-trip gets a 1-bit XOR swizzle.
  float bias[4];
#pragma unroll
  for (int j = 0; j < 4; ++j)
    bias[j] = ce[e * HID + nx * 128 + wn * 64 + j * 16 + fr];

  int lr = lane >> 2;
#pragma unroll
  for (int i = 0; i < 4; ++i) {
    __syncthreads();
#pragma unroll
    for (int j = 0; j < 4; ++j)
#pragma unroll
      for (int rg = 0; rg < 4; ++rg) {
        float v = acc[i][j][rg] + bias[j];
        v = v > 0.f ? v : 0.f;
        int row16 = fq * 4 + rg;
        int off = w * 2048 + row16 * 128 + (j * 16 + fr) * 2;
        off ^= (row16 & 1) << 6;
        *(unsigned short*)(smem + off) = f2bf(v);
      }
    __syncthreads();
    int R = wm * 64 + i * 16 + lr;
#pragma unroll
    for (int s = 0; s < 2; ++s) {
      int ch = (lane & 3) + s * 4;
      int off = w * 2048 + lr * 128 + ch * 16;
      off ^= (lr & 1) << 6;
      uint4 val = *(const uint4*)(smem + off);
      int ks2 = nx * 4 + wn * 2 + (ch >> 2);
      int kq = ch & 3;
      *(uint4*)(hp + (((size_t)(g * 32 + ks2) * 4 + kq) * 128 + R) * 8) = val;
    }
  }
}

// ---------------- phase 2: GEMM2  out[tok] = relu(h @ W2[e] + b2[e]) ---------
__global__ __launch_bounds__(256) void gemm2_k(
    const unsigned short* __restrict__ hp, const float* __restrict__ b2,
    const short* __restrict__ W2p, float* __restrict__ out,
    const int* __restrict__ idx, const int* __restrict__ cnt,
    const int* __restrict__ desc, const int* __restrict__ ntp) {
  int g, nx;
  decode_bid(blockIdx.x, g, nx);
  if (g >= *ntp) return;
  int e = desc[2 * g], rs = desc[2 * g + 1];
  int ce2 = cnt[e * CNTS];

  __shared__ __align__(16) char smem[32768];   // 2 x (8KB A + 8KB B)
  __shared__ int toks[128];

  int tid = threadIdx.x, lane = tid & 63, w = tid >> 6;
  int wm = w >> 1, wn = w & 1;
  int fr = lane & 15, fq = lane >> 4;

  if (tid < 128) toks[tid] = idx[e * BATCH + rs + tid];

  const char* Asrc = (const char*)hp + (size_t)g * 32 * 8192;
  const char* Bsrc = (const char*)W2p + (size_t)(e * 8 + nx) * 32 * 8192;

  // prologue: stage buf0 (ks=0), drain, sync
  lds_load16(smem + w * 1024,         Asrc + w * 1024 + lane * 16);
  lds_load16(smem + 4096 + w * 1024,  Asrc + 4096 + w * 1024 + lane * 16);
  lds_load16(smem + 8192 + w * 1024,  Bsrc + w * 1024 + lane * 16);
  lds_load16(smem + 12288 + w * 1024, Bsrc + 4096 + w * 1024 + lane * 16);
  asm volatile("s_waitcnt vmcnt(0)" ::: "memory");
  __builtin_amdgcn_s_barrier();

  f32x4 acc[4][4] = {};

  for (int ks = 0; ks < 32; ++ks) {
    int cur = ks & 1;
    char* nb = smem + (cur ^ 1) * 16384;
    if (ks < 31) {
      const char* as = Asrc + (ks + 1) * 8192;
      const char* bs = Bsrc + (ks + 1) * 8192;
      lds_load16(nb + w * 1024,         as + w * 1024 + lane * 16);
      lds_load16(nb + 4096 + w * 1024,  as + 4096 + w * 1024 + lane * 16);
      lds_load16(nb + 8192 + w * 1024,  bs + w * 1024 + lane * 16);
      lds_load16(nb + 12288 + w * 1024, bs + 4096 + w * 1024 + lane * 16);
    }
    const short* lA = (const short*)(smem + cur * 16384);
    const short* lB = (const short*)(smem + cur * 16384 + 8192);
    bf16x8 af[4], bfr[4];
#pragma unroll
    for (int i = 0; i < 4; ++i)
      af[i] = *(const bf16x8*)&lA[(fq * 128 + wm * 64 + i * 16 + fr) * 8];
#pragma unroll
    for (int j = 0; j < 4; ++j)
      bfr[j] = *(const bf16x8*)&lB[(fq * 128 + wn * 64 + j * 16 + fr) * 8];
#pragma unroll
    for (int i = 0; i < 4; ++i)
#pragma unroll
      for (int j = 0; j < 4; ++j)
        acc[i][j] = __builtin_amdgcn_mfma_f32_16x16x32_bf16(af[i], bfr[j], acc[i][j], 0, 0, 0);
    asm volatile("s_waitcnt vmcnt(0)" ::: "memory");
    __builtin_amdgcn_s_barrier();
  }

  // epilogue: bias + relu + scatter to out rows, coalesced via LDS round-trip.
  float bias[4];
#pragma unroll
  for (int j = 0; j < 4; ++j)
    bias[j] = b2[e * HID + nx * 128 + wn * 64 + j * 16 + fr];

  int lr = lane >> 2;
#pragma unroll
  for (int i = 0; i < 4; ++i) {
    __syncthreads();
#pragma unroll
    for (int j = 0; j < 4; ++j)
#pragma unroll
      for (int rg = 0; rg < 4; ++rg) {
        float v = acc[i][j][rg] + bias[j];
        int row16 = fq * 4 + rg;
        int off = w * 4096 + row16 * 256 + (j * 16 + fr) * 4;
        off ^= (row16 & 1) << 6;
        *(float*)(smem + off) = v > 0.f ? v : 0.f;
      }
    __syncthreads();
    int R = wm * 64 + i * 16 + lr;
    if (R < ce2 - rs) {
      float* orow = out + (size_t)toks[R] * HID + nx * 128 + wn * 64;
#pragma unroll
      for (int s = 0; s < 4; ++s) {
        int ch = (lane & 3) + s * 4;
        int off = w * 4096 + lr * 256 + ch * 16;
        off ^= (lr & 1) << 6;
        *(float4*)(orow + ch * 4) = *(const float4*)(smem + off);
      }
    }
  }
}

// ---------------- workspace layout (bytes) ----------------
// cnt     @ 0          (512)          — zeroed (with ce) by one memset
// ce      @ 512        (32768)        -> 33280
// ntiles  @ 33280      (4)
// desc    @ 33344      (1088)         -> 34432
// idx     @ 36864      (524288)       -> 561152
// W1p     @ 561152     (16777216)     -> 17338368
// W2p     @ 17338368   (16777216)     -> 34115584
// hp      @ 34115584   (35651584)     -> 69767168
// xb      @ 69767168   (33554432)     -> 103321600 (~103.3 MB)

extern "C" void kernel_launch(void* const* d_in, const int* in_sizes, int n_in,
                              void* d_out, int out_size, void* d_ws, size_t ws_size,
                              hipStream_t stream) {
  const float* x   = (const float*)d_in[0];
  const int*   ops = (const int*)d_in[1];
  const float* emb = (const float*)d_in[2];
  const float* W1  = (const float*)d_in[3];
  const float* b1  = (const float*)d_in[4];
  const float* W2  = (const float*)d_in[5];
  const float* b2  = (const float*)d_in[6];
  float* out = (float*)d_out;

  char* ws = (char*)d_ws;
  int* cnt  = (int*)(ws + 0);
  float* ce = (float*)(ws + 512);
  int* ntp  = (int*)(ws + 33280);
  int* desc = (int*)(ws + 33344);
  int* idx  = (int*)(ws + 36864);
  short* W1p = (short*)(ws + 561152);
  short* W2p = (short*)(ws + 17338368);
  unsigned short* hp = (unsigned short*)(ws + 34115584);
  unsigned int* xb = (unsigned int*)(ws + 69767168);

  hipMemsetAsync(ws, 0, 33280, stream);   // cnt + ce
  bucket_ce_k<<<2240 + 4096, 256, 0, stream>>>(ops, cnt, idx, W1, emb, b1, ce, W1p, x, xb);
  schedule_k<<<1, 256, 0, stream>>>(cnt, desc, ntp, idx);
  gemm1_w2_k<<<8 * MAXT + 2048, 256, 0, stream>>>(xb, idx, ce, W1p, hp, desc, ntp, W2, W2p);
  gemm2_k<<<8 * MAXT, 256, 0, stream>>>(hp, b2, W2p, out, idx, cnt, desc, ntp);
}

// Round 4
// 304.196 us; speedup vs baseline: 1.0094x; 1.0094x over previous
//
#include <hip/hip_runtime.h>
#include <hip/hip_bf16.h>

#define BATCH 16384
#define HID   1024
#define EMBD  512
#define NOPS  8
#define MAXT  136   // max tile slots: sum ceil(cnt_e/128) <= 135
#define CNTS  16    // cnt stride in ints (64 B) — one cache line per expert

typedef __attribute__((ext_vector_type(8))) short bf16x8;
typedef __attribute__((ext_vector_type(4))) float f32x4;

__device__ __forceinline__ unsigned short f2bf(float f) {
  unsigned int u = __float_as_uint(f);
  u += 0x7FFF + ((u >> 16) & 1);
  return (unsigned short)(u >> 16);
}

__device__ __forceinline__ unsigned int pk2(float a, float b) {
  __hip_bfloat162 t = __float22bfloat162_rn(make_float2(a, b));
  return *(unsigned int*)(&t);
}

__device__ __forceinline__ void lds_load16(void* lds, const void* g) {
  __builtin_amdgcn_global_load_lds(
      (const __attribute__((address_space(1))) unsigned int*)g,
      (__attribute__((address_space(3))) unsigned int*)lds, 16, 0, 0);
}

// XCD-locality decode: linear blocks round-robin across 8 XCDs, so bid&7 is
// the XCD. All 8 nx-blocks of a g land on one XCD (A-slab L2 reuse), and each
// XCD covers contiguous g-range [17c, 17c+17) ~= one expert (W-slab in L2).
__device__ __forceinline__ void decode_bid(int bid, int& g, int& nx) {
  g = 17 * (bid & 7) + (bid >> 6);
  nx = (bid >> 3) & 7;
}

// schedule_k replacement: each block derives (e, rs) for its tile g from the
// 8 cnt values with a scalar prefix scan (uniform -> SGPR). Returns -1 if
// g >= total tile count.
__device__ __forceinline__ int decode_tile(const int* __restrict__ cnt,
                                           int g, int& rs, int& ce_cnt) {
  int e = -1, at = 0;
  rs = 0; ce_cnt = 0;
#pragma unroll
  for (int o = 0; o < NOPS; ++o) {
    int c = cnt[o * CNTS];
    int t = (c + 127) >> 7;
    if (e < 0 && g < at + t) { e = o; rs = (g - at) * 128; ce_cnt = c; }
    at += t;
  }
  return e;
}

// LDS-free weight transpose tile, fq-major slab layout:
//   slab[kq][n][kk] bf16 (kq=k/8 in 0..3, n in 0..127, kk=k%8)
//   value = W[ks*32 + kq*8 + kk][nx*128 + n]
// Fragment ds_read (fq*128+row)*16B hits each bank-quad twice per wave
// (2-way = free, m136) -> conflict-free fragment reads.
__device__ __forceinline__ void w_prep_tile(const float* __restrict__ W,
                                            short* __restrict__ Wp,
                                            int ks, int nx, int tid) {
  int n = tid & 127, kh = tid >> 7;           // kh: low/high 16 of the 32-k tile
  const float* src = W + (size_t)(ks * 32 + kh * 16) * 1024 + nx * 128 + n;
  float v[16];
#pragma unroll
  for (int kk = 0; kk < 16; ++kk) v[kk] = src[(size_t)kk * 1024];
  uint4 a, b;
  a.x = pk2(v[0], v[1]);  a.y = pk2(v[2], v[3]);
  a.z = pk2(v[4], v[5]);  a.w = pk2(v[6], v[7]);
  b.x = pk2(v[8], v[9]);  b.y = pk2(v[10], v[11]);
  b.z = pk2(v[12], v[13]); b.w = pk2(v[14], v[15]);
  uint4* dst = (uint4*)Wp;
  dst[(2 * kh) * 128 + n]     = a;            // kq = 2*kh   (k 0..7 of this half)
  dst[(2 * kh + 1) * 128 + n] = b;            // kq = 2*kh+1 (k 8..15)
}

// ---- phase 0: bucket (64) + ce (128) + W1 prep (2048) + xb convert (4096) ---
// xb = bf16(x) in token order — bucket-independent, so it rides in phase 0.
// gemm1 then gathers A rows straight from xb via per-lane global_load_lds
// (no Ap slab, no prep kernel, no VALU repack on the gemm critical path).
// ce[e][n] = b1[e][n] + sum_k emb[e][k] * W1[e][1024+k][n] — embedding half of
// GEMM1 collapses to a per-(expert,n) constant, cutting GEMM1 K 1536 -> 1024.
__global__ void bucket_ce_k(const int* __restrict__ ops, int* __restrict__ cnt,
                            int* __restrict__ idx, const float* __restrict__ W1,
                            const float* __restrict__ emb,
                            const float* __restrict__ b1, float* __restrict__ ce,
                            short* __restrict__ W1p, const float* __restrict__ x,
                            unsigned int* __restrict__ xb) {
  int bid = blockIdx.x;
  int tid = threadIdx.x;
  if (bid >= 2240) {
    // ---- xb path: f32 -> bf16, 4096 blocks * 4096 elems ----
    size_t i = ((size_t)(bid - 2240) * 256 + tid) * 16;
    const float4* src = (const float4*)(x + i);
    float4 f0 = src[0], f1 = src[1], f2v = src[2], f3 = src[3];
    uint4 p0 = make_uint4(pk2(f0.x, f0.y), pk2(f0.z, f0.w),
                          pk2(f1.x, f1.y), pk2(f1.z, f1.w));
    uint4 p1 = make_uint4(pk2(f2v.x, f2v.y), pk2(f2v.z, f2v.w),
                          pk2(f3.x, f3.y), pk2(f3.z, f3.w));
    uint4* dst = (uint4*)(xb + i / 2);
    dst[0] = p0;
    dst[1] = p1;
    return;
  }
  if (bid >= 192) {
    // ---- W1 path: 8 e * 8 nx * 32 ks (first 1024 rows only) ----
    int b = bid - 192;
    int e = b / 256; int rr = b % 256; int nx = rr / 32, ks = rr % 32;
    w_prep_tile(W1 + (size_t)e * 1536 * 1024,
                W1p + ((size_t)(e * 8 + nx) * 32 + ks) * 4096, ks, nx, tid);
    return;
  }
  if (bid >= 64) {
    // ---- ce path ----
    int cb = bid - 64;
    int e = cb >> 4, kp = cb & 15;
    int n = tid * 4;
    const float* Wc = W1 + (size_t)e * 1536 * 1024 + (size_t)(1024 + kp * 32) * 1024 + n;
    const float* ee = emb + e * EMBD + kp * 32;
    float4 a = make_float4(0.f, 0.f, 0.f, 0.f);
#pragma unroll
    for (int kk = 0; kk < 32; ++kk) {
      float s = ee[kk];
      float4 r = *(const float4*)(Wc + (size_t)kk * 1024);
      a.x += s * r.x; a.y += s * r.y; a.z += s * r.z; a.w += s * r.w;
    }
    if (kp == 0) {
      float4 b = *(const float4*)(b1 + e * HID + n);
      a.x += b.x; a.y += b.y; a.z += b.z; a.w += b.w;
    }
    float* d = ce + e * HID + n;
    atomicAdd(d + 0, a.x); atomicAdd(d + 1, a.y);
    atomicAdd(d + 2, a.z); atomicAdd(d + 3, a.w);
    return;
  }
  // ---- bucket path (block-aggregated atomics) ----
  __shared__ int wcnt[4][NOPS];
  __shared__ int wbase[4][NOPS];
  int lane = tid & 63, w = tid >> 6;
  int t = bid * 256 + tid;
  int op = ops[t];
  unsigned long long msave = 0;
#pragma unroll
  for (int o = 0; o < NOPS; ++o) {
    unsigned long long mm = __ballot(op == o);
    if (op == o) msave = mm;
    if (lane == o) wcnt[w][o] = __popcll(mm);
  }
  __syncthreads();
  if (tid < NOPS) {
    int c0 = wcnt[0][tid], c1 = wcnt[1][tid], c2 = wcnt[2][tid], c3 = wcnt[3][tid];
    int base = atomicAdd(&cnt[tid * CNTS], c0 + c1 + c2 + c3);
    wbase[0][tid] = base;
    wbase[1][tid] = base + c0;
    wbase[2][tid] = base + c0 + c1;
    wbase[3][tid] = base + c0 + c1 + c2;
  }
  __syncthreads();
  int pre = __popcll(msave & ((1ull << lane) - 1ull));
  idx[op * BATCH + wbase[w][op] + pre] = t;
}

// ---------------- phase 1: GEMM1 gathered-DMA A (1088) + W2 prep (2048) ------
// h = relu(x_tile @ W1[e][:1024] + ce[e]); K = 1024 (32 iters).
// 2-phase double-buffer, UNROLLED x2 with named static buffers s0/s1 (rule
// #20: round-3's runtime `cur^1` indexing forced per-iter address recompute —
// VALUBusy 11->30%, net -12%). Static bases fold all ds_read addresses into
// one VGPR + imm offsets; staging ptrs become loop-carried adds.
// STAGE(ks+1) issued before MFMA(ks); one vmcnt(0)+s_barrier per K-step.
__global__ __launch_bounds__(256) void gemm1_w2_k(
    const unsigned int* __restrict__ xb, const int* __restrict__ idx,
    const float* __restrict__ ce, const short* __restrict__ W1p,
    unsigned short* __restrict__ hp, const int* __restrict__ cnt,
    const float* __restrict__ W2, short* __restrict__ W2p) {
  int bid = blockIdx.x;
  int tid = threadIdx.x;
  if (bid >= 8 * MAXT) {
    // ---- W2 path: 8 e * 8 nx * 32 ks ----
    int b = bid - 8 * MAXT;
    int e = b / 256; int rr = b % 256; int nx = rr / 32, ks = rr % 32;
    w_prep_tile(W2 + (size_t)e * 1024 * 1024,
                W2p + ((size_t)(e * 8 + nx) * 32 + ks) * 4096, ks, nx, tid);
    return;
  }
  int g, nx;
  decode_bid(bid, g, nx);
  int rs, ce_cnt;
  int e = decode_tile(cnt, g, rs, ce_cnt);
  if (e < 0) return;

  __shared__ __align__(16) char smem[32768];   // 2 x (8KB A + 8KB B)
  char* s0 = smem;
  char* s1 = smem + 16384;

  int lane = tid & 63, w = tid >> 6;
  int wm = w >> 1, wn = w & 1;
  int fr = lane & 15, fq = lane >> 4;

  // gathered A sources: lane i of wave w stages rows lane / 64+lane, kq=w.
  // Clamped reads replace idx padding (pad slots are uninitialized now).
  int p0 = rs + lane, p1 = rs + 64 + lane;
  int t0 = (p0 < ce_cnt) ? idx[e * BATCH + p0] : 0;
  int t1 = (p1 < ce_cnt) ? idx[e * BATCH + p1] : 0;
  const char* a0 = (const char*)xb + (size_t)t0 * 2048 + w * 16;
  const char* a1 = (const char*)xb + (size_t)t1 * 2048 + w * 16;
  const char* Bsrc = (const char*)W1p + (size_t)(e * 8 + nx) * 32 * 8192;

  // prologue: stage buf0 (ks=0), drain, sync
  lds_load16(s0 + w * 2048,         a0);
  lds_load16(s0 + w * 2048 + 1024,  a1);
  lds_load16(s0 + 8192 + w * 1024,  Bsrc + w * 1024 + lane * 16);
  lds_load16(s0 + 12288 + w * 1024, Bsrc + 4096 + w * 1024 + lane * 16);
  asm volatile("s_waitcnt vmcnt(0)" ::: "memory");
  __builtin_amdgcn_s_barrier();

  f32x4 acc[4][4] = {};
  int fo = (fq * 128 + wm * 64 + fr) * 8;   // A-frag base (shorts)
  int bo = (fq * 128 + wn * 64 + fr) * 8;   // B-frag base (shorts)

#define G1_STEP(CURB, NXTB, KS)                                               \
  {                                                                           \
    if ((KS) < 31) {                                                          \
      const char* bs_ = Bsrc + ((KS) + 1) * 8192;                             \
      lds_load16((NXTB) + w * 2048,         a0 + ((KS) + 1) * 64);            \
      lds_load16((NXTB) + w * 2048 + 1024,  a1 + ((KS) + 1) * 64);            \
      lds_load16((NXTB) + 8192 + w * 1024,  bs_ + w * 1024 + lane * 16);      \
      lds_load16((NXTB) + 12288 + w * 1024, bs_ + 4096 + w * 1024 + lane * 16); \
    }                                                                         \
    const short* lA_ = (const short*)(CURB);                                  \
    const short* lB_ = (const short*)((CURB) + 8192);                         \
    bf16x8 af[4], bfr[4];                                                     \
    _Pragma("unroll")                                                         \
    for (int i = 0; i < 4; ++i) af[i] = *(const bf16x8*)&lA_[fo + i * 128];   \
    _Pragma("unroll")                                                         \
    for (int j = 0; j < 4; ++j) bfr[j] = *(const bf16x8*)&lB_[bo + j * 128];  \
    _Pragma("unroll")                                                         \
    for (int i = 0; i < 4; ++i)                                               \
      _Pragma("unroll")                                                       \
      for (int j = 0; j < 4; ++j)                                             \
        acc[i][j] = __builtin_amdgcn_mfma_f32_16x16x32_bf16(af[i], bfr[j],    \
                                                            acc[i][j], 0, 0, 0); \
    asm volatile("s_waitcnt vmcnt(0)" ::: "memory");                          \
    __builtin_amdgcn_s_barrier();                                             \
  }

  for (int ks = 0; ks < 32; ks += 2) {
    G1_STEP(s0, s1, ks);
    G1_STEP(s1, s0, ks + 1);
  }
#undef G1_STEP

  // epilogue: +ce (bias incl. embedding term) + relu + bf16, coalesced via LDS.
  // hp layout (fq-major): [g][ks2(32)][kq(4)][128 r][8 k] — gemm2 staging is a
  // linear 8 KB slab copy. LDS round-trip gets a 1-bit XOR swizzle.
  float bias[4];
#pragma unroll
  for (int j = 0; j < 4; ++j)
    bias[j] = ce[e * HID + nx * 128 + wn * 64 + j * 16 + fr];

  int lr = lane >> 2;
#pragma unroll
  for (int i = 0; i < 4; ++i) {
    __syncthreads();
#pragma unroll
    for (int j = 0; j < 4; ++j)
#pragma unroll
      for (int rg = 0; rg < 4; ++rg) {
        float v = acc[i][j][rg] + bias[j];
        v = v > 0.f ? v : 0.f;
        int row16 = fq * 4 + rg;
        int off = w * 2048 + row16 * 128 + (j * 16 + fr) * 2;
        off ^= (row16 & 1) << 6;
        *(unsigned short*)(smem + off) = f2bf(v);
      }
    __syncthreads();
    int R = wm * 64 + i * 16 + lr;
#pragma unroll
    for (int s = 0; s < 2; ++s) {
      int ch = (lane & 3) + s * 4;
      int off = w * 2048 + lr * 128 + ch * 16;
      off ^= (lr & 1) << 6;
      uint4 val = *(const uint4*)(smem + off);
      int ks2 = nx * 4 + wn * 2 + (ch >> 2);
      int kq = ch & 3;
      *(uint4*)(hp + (((size_t)(g * 32 + ks2) * 4 + kq) * 128 + R) * 8) = val;
    }
  }
}

// ---------------- phase 2: GEMM2  out[tok] = relu(h @ W2[e] + b2[e]) ---------
__global__ __launch_bounds__(256) void gemm2_k(
    const unsigned short* __restrict__ hp, const float* __restrict__ b2,
    const short* __restrict__ W2p, float* __restrict__ out,
    const int* __restrict__ idx, const int* __restrict__ cnt) {
  int g, nx;
  decode_bid(blockIdx.x, g, nx);
  int rs, ce_cnt;
  int e = decode_tile(cnt, g, rs, ce_cnt);
  if (e < 0) return;

  __shared__ __align__(16) char smem[32768];   // 2 x (8KB A + 8KB B)
  __shared__ int toks[128];
  char* s0 = smem;
  char* s1 = smem + 16384;

  int tid = threadIdx.x, lane = tid & 63, w = tid >> 6;
  int wm = w >> 1, wn = w & 1;
  int fr = lane & 15, fq = lane >> 4;

  if (tid < 128) {
    int p = rs + tid;
    toks[tid] = (p < ce_cnt) ? idx[e * BATCH + p] : 0;
  }

  const char* Asrc = (const char*)hp + (size_t)g * 32 * 8192;
  const char* Bsrc = (const char*)W2p + (size_t)(e * 8 + nx) * 32 * 8192;

  // prologue: stage buf0 (ks=0), drain, sync
  lds_load16(s0 + w * 1024,         Asrc + w * 1024 + lane * 16);
  lds_load16(s0 + 4096 + w * 1024,  Asrc + 4096 + w * 1024 + lane * 16);
  lds_load16(s0 + 8192 + w * 1024,  Bsrc + w * 1024 + lane * 16);
  lds_load16(s0 + 12288 + w * 1024, Bsrc + 4096 + w * 1024 + lane * 16);
  asm volatile("s_waitcnt vmcnt(0)" ::: "memory");
  __builtin_amdgcn_s_barrier();

  f32x4 acc[4][4] = {};
  int fo = (fq * 128 + wm * 64 + fr) * 8;
  int bo = (fq * 128 + wn * 64 + fr) * 8;

#define G2_STEP(CURB, NXTB, KS)                                               \
  {                                                                           \
    if ((KS) < 31) {                                                          \
      const char* as_ = Asrc + ((KS) + 1) * 8192;                             \
      const char* bs_ = Bsrc + ((KS) + 1) * 8192;                             \
      lds_load16((NXTB) + w * 1024,         as_ + w * 1024 + lane * 16);      \
      lds_load16((NXTB) + 4096 + w * 1024,  as_ + 4096 + w * 1024 + lane * 16); \
      lds_load16((NXTB) + 8192 + w * 1024,  bs_ + w * 1024 + lane * 16);      \
      lds_load16((NXTB) + 12288 + w * 1024, bs_ + 4096 + w * 1024 + lane * 16); \
    }                                                                         \
    const short* lA_ = (const short*)(CURB);                                  \
    const short* lB_ = (const short*)((CURB) + 8192);                         \
    bf16x8 af[4], bfr[4];                                                     \
    _Pragma("unroll")                                                         \
    for (int i = 0; i < 4; ++i) af[i] = *(const bf16x8*)&lA_[fo + i * 128];   \
    _Pragma("unroll")                                                         \
    for (int j = 0; j < 4; ++j) bfr[j] = *(const bf16x8*)&lB_[bo + j * 128];  \
    _Pragma("unroll")                                                         \
    for (int i = 0; i < 4; ++i)                                               \
      _Pragma("unroll")                                                       \
      for (int j = 0; j < 4; ++j)                                             \
        acc[i][j] = __builtin_amdgcn_mfma_f32_16x16x32_bf16(af[i], bfr[j],    \
                                                            acc[i][j], 0, 0, 0); \
    asm volatile("s_waitcnt vmcnt(0)" ::: "memory");                          \
    __builtin_amdgcn_s_barrier();                                             \
  }

  for (int ks = 0; ks < 32; ks += 2) {
    G2_STEP(s0, s1, ks);
    G2_STEP(s1, s0, ks + 1);
  }
#undef G2_STEP

  // epilogue: bias + relu + scatter to out rows, coalesced via LDS round-trip.
  float bias[4];
#pragma unroll
  for (int j = 0; j < 4; ++j)
    bias[j] = b2[e * HID + nx * 128 + wn * 64 + j * 16 + fr];

  int lr = lane >> 2;
#pragma unroll
  for (int i = 0; i < 4; ++i) {
    __syncthreads();
#pragma unroll
    for (int j = 0; j < 4; ++j)
#pragma unroll
      for (int rg = 0; rg < 4; ++rg) {
        float v = acc[i][j][rg] + bias[j];
        int row16 = fq * 4 + rg;
        int off = w * 4096 + row16 * 256 + (j * 16 + fr) * 4;
        off ^= (row16 & 1) << 6;
        *(float*)(smem + off) = v > 0.f ? v : 0.f;
      }
    __syncthreads();
    int R = wm * 64 + i * 16 + lr;
    if (R < ce_cnt - rs) {
      float* orow = out + (size_t)toks[R] * HID + nx * 128 + wn * 64;
#pragma unroll
      for (int s = 0; s < 4; ++s) {
        int ch = (lane & 3) + s * 4;
        int off = w * 4096 + lr * 256 + ch * 16;
        off ^= (lr & 1) << 6;
        *(float4*)(orow + ch * 4) = *(const float4*)(smem + off);
      }
    }
  }
}

// ---------------- workspace layout (bytes) ----------------
// cnt     @ 0          (512)          — zeroed (with ce) by one memset
// ce      @ 512        (32768)        -> 33280
// (desc/ntp slots retired — schedule_k removed; blocks decode from cnt)
// idx     @ 36864      (524288)       -> 561152
// W1p     @ 561152     (16777216)     -> 17338368
// W2p     @ 17338368   (16777216)     -> 34115584
// hp      @ 34115584   (35651584)     -> 69767168
// xb      @ 69767168   (33554432)     -> 103321600 (~103.3 MB)

extern "C" void kernel_launch(void* const* d_in, const int* in_sizes, int n_in,
                              void* d_out, int out_size, void* d_ws, size_t ws_size,
                              hipStream_t stream) {
  const float* x   = (const float*)d_in[0];
  const int*   ops = (const int*)d_in[1];
  const float* emb = (const float*)d_in[2];
  const float* W1  = (const float*)d_in[3];
  const float* b1  = (const float*)d_in[4];
  const float* W2  = (const float*)d_in[5];
  const float* b2  = (const float*)d_in[6];
  float* out = (float*)d_out;

  char* ws = (char*)d_ws;
  int* cnt  = (int*)(ws + 0);
  float* ce = (float*)(ws + 512);
  int* idx  = (int*)(ws + 36864);
  short* W1p = (short*)(ws + 561152);
  short* W2p = (short*)(ws + 17338368);
  unsigned short* hp = (unsigned short*)(ws + 34115584);
  unsigned int* xb = (unsigned int*)(ws + 69767168);

  hipMemsetAsync(ws, 0, 33280, stream);   // cnt + ce
  bucket_ce_k<<<2240 + 4096, 256, 0, stream>>>(ops, cnt, idx, W1, emb, b1, ce, W1p, x, xb);
  gemm1_w2_k<<<8 * MAXT + 2048, 256, 0, stream>>>(xb, idx, ce, W1p, hp, cnt, W2, W2p);
  gemm2_k<<<8 * MAXT, 256, 0, stream>>>(hp, b2, W2p, out, idx, cnt);
}

// Round 7
// 295.229 us; speedup vs baseline: 1.0401x; 1.0304x over previous
//
#include <hip/hip_runtime.h>
#include <hip/hip_bf16.h>

#define BATCH 16384
#define HID   1024
#define EMBD  512
#define NOPS  8
#define MAXT  136   // max tile slots: sum ceil(cnt_e/128) <= 135
#define CNTS  16    // cnt stride in ints (64 B) — one cache line per expert

typedef __attribute__((ext_vector_type(8))) short bf16x8;
typedef __attribute__((ext_vector_type(4))) float f32x4;

#define VMWAIT(N) asm volatile("s_waitcnt vmcnt(" #N ")" ::: "memory")
// raw s_barrier is NO-MEM to LLVM IR (that's why __syncthreads wraps it in
// fences) and sched_barrier(0) only constrains the MIR scheduler — IR passes
// can hoist LDS reads / global_load_lds issues above the barrier (round-6
// absmax fail: cross-wave fragments read before other waves' VMWAIT, and
// staging into (ks+2)%3 == (ks-1)%3 hoisted into the previous step). The
// empty asm with "memory" clobber is a zero-inst compiler fence on BOTH sides.
#define BARRIER_FENCED()                      \
  do {                                        \
    asm volatile("" ::: "memory");            \
    __builtin_amdgcn_s_barrier();             \
    asm volatile("" ::: "memory");            \
    __builtin_amdgcn_sched_barrier(0);        \
  } while (0)

__device__ __forceinline__ unsigned short f2bf(float f) {
  unsigned int u = __float_as_uint(f);
  u += 0x7FFF + ((u >> 16) & 1);
  return (unsigned short)(u >> 16);
}

__device__ __forceinline__ unsigned int pk2(float a, float b) {
  __hip_bfloat162 t = __float22bfloat162_rn(make_float2(a, b));
  return *(unsigned int*)(&t);
}

__device__ __forceinline__ void lds_load16(void* lds, const void* g) {
  __builtin_amdgcn_global_load_lds(
      (const __attribute__((address_space(1))) unsigned int*)g,
      (__attribute__((address_space(3))) unsigned int*)lds, 16, 0, 0);
}

// XCD-locality decode: linear blocks round-robin across 8 XCDs, so bid&7 is
// the XCD. All 8 nx-blocks of a g land on one XCD (A-slab L2 reuse), and each
// XCD covers contiguous g-range [17c, 17c+17) ~= one expert (W-slab in L2).
__device__ __forceinline__ void decode_bid(int bid, int& g, int& nx) {
  g = 17 * (bid & 7) + (bid >> 6);
  nx = (bid >> 3) & 7;
}

// schedule_k replacement: each block derives (e, rs) for its tile g from the
// 8 cnt values with a scalar prefix scan (uniform -> SGPR). Returns -1 if
// g >= total tile count.
__device__ __forceinline__ int decode_tile(const int* __restrict__ cnt,
                                           int g, int& rs, int& ce_cnt) {
  int e = -1, at = 0;
  rs = 0; ce_cnt = 0;
#pragma unroll
  for (int o = 0; o < NOPS; ++o) {
    int c = cnt[o * CNTS];
    int t = (c + 127) >> 7;
    if (e < 0 && g < at + t) { e = o; rs = (g - at) * 128; ce_cnt = c; }
    at += t;
  }
  return e;
}

// LDS-free weight transpose tile, fq-major slab layout:
//   slab[kq][n][kk] bf16 (kq=k/8 in 0..3, n in 0..127, kk=k%8)
//   value = W[ks*32 + kq*8 + kk][nx*128 + n]
// Fragment ds_read (fq*128+row)*16B hits each bank-quad twice per wave
// (2-way = free, m136) -> conflict-free fragment reads.
__device__ __forceinline__ void w_prep_tile(const float* __restrict__ W,
                                            short* __restrict__ Wp,
                                            int ks, int nx, int tid) {
  int n = tid & 127, kh = tid >> 7;           // kh: low/high 16 of the 32-k tile
  const float* src = W + (size_t)(ks * 32 + kh * 16) * 1024 + nx * 128 + n;
  float v[16];
#pragma unroll
  for (int kk = 0; kk < 16; ++kk) v[kk] = src[(size_t)kk * 1024];
  uint4 a, b;
  a.x = pk2(v[0], v[1]);  a.y = pk2(v[2], v[3]);
  a.z = pk2(v[4], v[5]);  a.w = pk2(v[6], v[7]);
  b.x = pk2(v[8], v[9]);  b.y = pk2(v[10], v[11]);
  b.z = pk2(v[12], v[13]); b.w = pk2(v[14], v[15]);
  uint4* dst = (uint4*)Wp;
  dst[(2 * kh) * 128 + n]     = a;            // kq = 2*kh   (k 0..7 of this half)
  dst[(2 * kh + 1) * 128 + n] = b;            // kq = 2*kh+1 (k 8..15)
}

// ---- phase 0: bucket (64) + ce (128) + W1 prep (2048) + xb convert (4096) ---
// xb = bf16(x) in token order — bucket-independent, so it rides in phase 0.
// gemm1 then gathers A rows straight from xb via per-lane global_load_lds
// (no Ap slab, no prep kernel, no VALU repack on the gemm critical path).
// ce[e][n] = b1[e][n] + sum_k emb[e][k] * W1[e][1024+k][n] — embedding half of
// GEMM1 collapses to a per-(expert,n) constant, cutting GEMM1 K 1536 -> 1024.
__global__ void bucket_ce_k(const int* __restrict__ ops, int* __restrict__ cnt,
                            int* __restrict__ idx, const float* __restrict__ W1,
                            const float* __restrict__ emb,
                            const float* __restrict__ b1, float* __restrict__ ce,
                            short* __restrict__ W1p, const float* __restrict__ x,
                            unsigned int* __restrict__ xb) {
  int bid = blockIdx.x;
  int tid = threadIdx.x;
  if (bid >= 2240) {
    // ---- xb path: f32 -> bf16, 4096 blocks * 4096 elems ----
    size_t i = ((size_t)(bid - 2240) * 256 + tid) * 16;
    const float4* src = (const float4*)(x + i);
    float4 f0 = src[0], f1 = src[1], f2v = src[2], f3 = src[3];
    uint4 p0 = make_uint4(pk2(f0.x, f0.y), pk2(f0.z, f0.w),
                          pk2(f1.x, f1.y), pk2(f1.z, f1.w));
    uint4 p1 = make_uint4(pk2(f2v.x, f2v.y), pk2(f2v.z, f2v.w),
                          pk2(f3.x, f3.y), pk2(f3.z, f3.w));
    uint4* dst = (uint4*)(xb + i / 2);
    dst[0] = p0;
    dst[1] = p1;
    return;
  }
  if (bid >= 192) {
    // ---- W1 path: 8 e * 8 nx * 32 ks (first 1024 rows only) ----
    int b = bid - 192;
    int e = b / 256; int rr = b % 256; int nx = rr / 32, ks = rr % 32;
    w_prep_tile(W1 + (size_t)e * 1536 * 1024,
                W1p + ((size_t)(e * 8 + nx) * 32 + ks) * 4096, ks, nx, tid);
    return;
  }
  if (bid >= 64) {
    // ---- ce path ----
    int cb = bid - 64;
    int e = cb >> 4, kp = cb & 15;
    int n = tid * 4;
    const float* Wc = W1 + (size_t)e * 1536 * 1024 + (size_t)(1024 + kp * 32) * 1024 + n;
    const float* ee = emb + e * EMBD + kp * 32;
    float4 a = make_float4(0.f, 0.f, 0.f, 0.f);
#pragma unroll
    for (int kk = 0; kk < 32; ++kk) {
      float s = ee[kk];
      float4 r = *(const float4*)(Wc + (size_t)kk * 1024);
      a.x += s * r.x; a.y += s * r.y; a.z += s * r.z; a.w += s * r.w;
    }
    if (kp == 0) {
      float4 b = *(const float4*)(b1 + e * HID + n);
      a.x += b.x; a.y += b.y; a.z += b.z; a.w += b.w;
    }
    float* d = ce + e * HID + n;
    atomicAdd(d + 0, a.x); atomicAdd(d + 1, a.y);
    atomicAdd(d + 2, a.z); atomicAdd(d + 3, a.w);
    return;
  }
  // ---- bucket path (block-aggregated atomics) ----
  __shared__ int wcnt[4][NOPS];
  __shared__ int wbase[4][NOPS];
  int lane = tid & 63, w = tid >> 6;
  int t = bid * 256 + tid;
  int op = ops[t];
  unsigned long long msave = 0;
#pragma unroll
  for (int o = 0; o < NOPS; ++o) {
    unsigned long long mm = __ballot(op == o);
    if (op == o) msave = mm;
    if (lane == o) wcnt[w][o] = __popcll(mm);
  }
  __syncthreads();
  if (tid < NOPS) {
    int c0 = wcnt[0][tid], c1 = wcnt[1][tid], c2 = wcnt[2][tid], c3 = wcnt[3][tid];
    int base = atomicAdd(&cnt[tid * CNTS], c0 + c1 + c2 + c3);
    wbase[0][tid] = base;
    wbase[1][tid] = base + c0;
    wbase[2][tid] = base + c0 + c1;
    wbase[3][tid] = base + c0 + c1 + c2;
  }
  __syncthreads();
  int pre = __popcll(msave & ((1ull << lane) - 1ull));
  idx[op * BATCH + wbase[w][op] + pre] = t;
}

// ---------------- phase 1: GEMM1 gathered-DMA A (1088) + W2 prep (2048) ------
// h = relu(x_tile @ W1[e][:1024] + ce[e]); K = 1024 (32 iters).
// 3-buffer counted-vmcnt pipeline (T4): stage ks+2 during step ks; steady wait
// is vmcnt(4) — the 4 loads for ks+2 stay in flight ACROSS the barrier, and
// ks+1's loads got a full extra K-step of cover. Buffer rotation fully static
// (period-3 unroll, rule #20); staging addrs are loop-carried pointer adds.
__global__ __launch_bounds__(256, 3) void gemm1_w2_k(
    const unsigned int* __restrict__ xb, const int* __restrict__ idx,
    const float* __restrict__ ce, const short* __restrict__ W1p,
    unsigned short* __restrict__ hp, const int* __restrict__ cnt,
    const float* __restrict__ W2, short* __restrict__ W2p) {
  int bid = blockIdx.x;
  int tid = threadIdx.x;
  if (bid >= 8 * MAXT) {
    // ---- W2 path: 8 e * 8 nx * 32 ks ----
    int b = bid - 8 * MAXT;
    int e = b / 256; int rr = b % 256; int nx = rr / 32, ks = rr % 32;
    w_prep_tile(W2 + (size_t)e * 1024 * 1024,
                W2p + ((size_t)(e * 8 + nx) * 32 + ks) * 4096, ks, nx, tid);
    return;
  }
  int g, nx;
  decode_bid(bid, g, nx);
  int rs, ce_cnt;
  int e = decode_tile(cnt, g, rs, ce_cnt);
  if (e < 0) return;

  __shared__ __align__(16) char smem[49152];   // 3 x (8KB A + 8KB B)
  char* s0 = smem;
  char* s1 = smem + 16384;
  char* s2 = smem + 32768;

  int lane = tid & 63, w = tid >> 6;
  int wm = w >> 1, wn = w & 1;
  int fr = lane & 15, fq = lane >> 4;

  // gathered A sources: lane i of wave w stages rows lane / 64+lane, kq=w.
  // Clamped reads replace idx padding (pad slots are uninitialized).
  int p0 = rs + lane, p1 = rs + 64 + lane;
  int t0 = (p0 < ce_cnt) ? idx[e * BATCH + p0] : 0;
  int t1 = (p1 < ce_cnt) ? idx[e * BATCH + p1] : 0;
  const char* pa0 = (const char*)xb + (size_t)t0 * 2048 + w * 16;
  const char* pa1 = (const char*)xb + (size_t)t1 * 2048 + w * 16;
  const char* pb0 = (const char*)W1p + (size_t)(e * 8 + nx) * 32 * 8192
                    + w * 1024 + lane * 16;
  const char* pb1 = pb0 + 4096;

#define G1_STAGE(NB)                                                          \
  {                                                                           \
    lds_load16((NB) + w * 2048,         pa0);                                 \
    lds_load16((NB) + w * 2048 + 1024,  pa1);                                 \
    lds_load16((NB) + 8192 + w * 1024,  pb0);                                 \
    lds_load16((NB) + 12288 + w * 1024, pb1);                                 \
    pa0 += 64; pa1 += 64; pb0 += 8192; pb1 += 8192;                           \
  }

#define G1_COMP(CB)                                                           \
  {                                                                           \
    const short* lA_ = (const short*)(CB);                                    \
    const short* lB_ = (const short*)((CB) + 8192);                           \
    bf16x8 af[4], bfr[4];                                                     \
    _Pragma("unroll")                                                         \
    for (int i = 0; i < 4; ++i) af[i] = *(const bf16x8*)&lA_[fo + i * 128];   \
    _Pragma("unroll")                                                         \
    for (int j = 0; j < 4; ++j) bfr[j] = *(const bf16x8*)&lB_[bo + j * 128];  \
    _Pragma("unroll")                                                         \
    for (int i = 0; i < 4; ++i)                                               \
      _Pragma("unroll")                                                       \
      for (int j = 0; j < 4; ++j)                                             \
        acc[i][j] = __builtin_amdgcn_mfma_f32_16x16x32_bf16(af[i], bfr[j],    \
                                                            acc[i][j], 0, 0, 0); \
  }

#define G1_STEP(CB, NB)                                                       \
  {                                                                           \
    G1_STAGE(NB);                                                             \
    G1_COMP(CB);                                                              \
    VMWAIT(4);                                                                \
    BARRIER_FENCED();                                                         \
  }

  // prologue: stage ks=0 -> s0, ks=1 -> s1; wait for s0 only (4 in flight)
  G1_STAGE(s0);
  G1_STAGE(s1);
  VMWAIT(4);
  BARRIER_FENCED();

  f32x4 acc[4][4] = {};
  int fo = (fq * 128 + wm * 64 + fr) * 8;   // A-frag base (shorts)
  int bo = (fq * 128 + wn * 64 + fr) * 8;   // B-frag base (shorts)

  for (int it = 0; it < 10; ++it) {         // ks = 0..29
    G1_STEP(s0, s2);
    G1_STEP(s1, s0);
    G1_STEP(s2, s1);
  }
  // ks = 30: nothing left to stage; need ks=31's loads (into s1) complete
  G1_COMP(s0);
  VMWAIT(0);
  BARRIER_FENCED();
  // ks = 31
  G1_COMP(s1);

#undef G1_STEP
#undef G1_COMP
#undef G1_STAGE

  // epilogue: +ce (bias incl. embedding term) + relu + bf16, coalesced via LDS.
  // hp layout (fq-major): [g][ks2(32)][kq(4)][128 r][8 k] — gemm2 staging is a
  // linear 8 KB slab copy. LDS round-trip gets a 1-bit XOR swizzle.
  float bias[4];
#pragma unroll
  for (int j = 0; j < 4; ++j)
    bias[j] = ce[e * HID + nx * 128 + wn * 64 + j * 16 + fr];

  int lr = lane >> 2;
#pragma unroll
  for (int i = 0; i < 4; ++i) {
    __syncthreads();
#pragma unroll
    for (int j = 0; j < 4; ++j)
#pragma unroll
      for (int rg = 0; rg < 4; ++rg) {
        float v = acc[i][j][rg] + bias[j];
        v = v > 0.f ? v : 0.f;
        int row16 = fq * 4 + rg;
        int off = w * 2048 + row16 * 128 + (j * 16 + fr) * 2;
        off ^= (row16 & 1) << 6;
        *(unsigned short*)(smem + off) = f2bf(v);
      }
    __syncthreads();
    int R = wm * 64 + i * 16 + lr;
#pragma unroll
    for (int s = 0; s < 2; ++s) {
      int ch = (lane & 3) + s * 4;
      int off = w * 2048 + lr * 128 + ch * 16;
      off ^= (lr & 1) << 6;
      uint4 val = *(const uint4*)(smem + off);
      int ks2 = nx * 4 + wn * 2 + (ch >> 2);
      int kq = ch & 3;
      *(uint4*)(hp + (((size_t)(g * 32 + ks2) * 4 + kq) * 128 + R) * 8) = val;
    }
  }
}

// ---------------- phase 2: GEMM2  out[tok] = relu(h @ W2[e] + b2[e]) ---------
__global__ __launch_bounds__(256, 3) void gemm2_k(
    const unsigned short* __restrict__ hp, const float* __restrict__ b2,
    const short* __restrict__ W2p, float* __restrict__ out,
    const int* __restrict__ idx, const int* __restrict__ cnt) {
  int g, nx;
  decode_bid(blockIdx.x, g, nx);
  int rs, ce_cnt;
  int e = decode_tile(cnt, g, rs, ce_cnt);
  if (e < 0) return;

  __shared__ __align__(16) char smem[49152];   // 3 x (8KB A + 8KB B)
  __shared__ int toks[128];
  char* s0 = smem;
  char* s1 = smem + 16384;
  char* s2 = smem + 32768;

  int tid = threadIdx.x, lane = tid & 63, w = tid >> 6;
  int wm = w >> 1, wn = w & 1;
  int fr = lane & 15, fq = lane >> 4;

  if (tid < 128) {
    int p = rs + tid;
    toks[tid] = (p < ce_cnt) ? idx[e * BATCH + p] : 0;
  }

  const char* Asrc = (const char*)hp + (size_t)g * 32 * 8192;
  const char* Bsrc = (const char*)W2p + (size_t)(e * 8 + nx) * 32 * 8192;
  const char* pA0 = Asrc + w * 1024 + lane * 16;
  const char* pA1 = pA0 + 4096;
  const char* pB0 = Bsrc + w * 1024 + lane * 16;
  const char* pB1 = pB0 + 4096;

#define G2_STAGE(NB)                                                          \
  {                                                                           \
    lds_load16((NB) + w * 1024,         pA0);                                 \
    lds_load16((NB) + 4096 + w * 1024,  pA1);                                 \
    lds_load16((NB) + 8192 + w * 1024,  pB0);                                 \
    lds_load16((NB) + 12288 + w * 1024, pB1);                                 \
    pA0 += 8192; pA1 += 8192; pB0 += 8192; pB1 += 8192;                       \
  }

#define G2_COMP(CB)                                                           \
  {                                                                           \
    const short* lA_ = (const short*)(CB);                                    \
    const short* lB_ = (const short*)((CB) + 8192);                           \
    bf16x8 af[4], bfr[4];                                                     \
    _Pragma("unroll")                                                         \
    for (int i = 0; i < 4; ++i) af[i] = *(const bf16x8*)&lA_[fo + i * 128];   \
    _Pragma("unroll")                                                         \
    for (int j = 0; j < 4; ++j) bfr[j] = *(const bf16x8*)&lB_[bo + j * 128];  \
    _Pragma("unroll")                                                         \
    for (int i = 0; i < 4; ++i)                                               \
      _Pragma("unroll")                                                       \
      for (int j = 0; j < 4; ++j)                                             \
        acc[i][j] = __builtin_amdgcn_mfma_f32_16x16x32_bf16(af[i], bfr[j],    \
                                                            acc[i][j], 0, 0, 0); \
  }

#define G2_STEP(CB, NB)                                                       \
  {                                                                           \
    G2_STAGE(NB);                                                             \
    G2_COMP(CB);                                                              \
    VMWAIT(4);                                                                \
    BARRIER_FENCED();                                                         \
  }

  // prologue: stage ks=0 -> s0, ks=1 -> s1
  G2_STAGE(s0);
  G2_STAGE(s1);
  VMWAIT(4);
  BARRIER_FENCED();

  f32x4 acc[4][4] = {};
  int fo = (fq * 128 + wm * 64 + fr) * 8;
  int bo = (fq * 128 + wn * 64 + fr) * 8;

  for (int it = 0; it < 10; ++it) {         // ks = 0..29
    G2_STEP(s0, s2);
    G2_STEP(s1, s0);
    G2_STEP(s2, s1);
  }
  G2_COMP(s0);          // ks = 30
  VMWAIT(0);
  BARRIER_FENCED();
  G2_COMP(s1);          // ks = 31

#undef G2_STEP
#undef G2_COMP
#undef G2_STAGE

  // epilogue: bias + relu + scatter to out rows, coalesced via LDS round-trip.
  float bias[4];
#pragma unroll
  for (int j = 0; j < 4; ++j)
    bias[j] = b2[e * HID + nx * 128 + wn * 64 + j * 16 + fr];

  int lr = lane >> 2;
#pragma unroll
  for (int i = 0; i < 4; ++i) {
    __syncthreads();
#pragma unroll
    for (int j = 0; j < 4; ++j)
#pragma unroll
      for (int rg = 0; rg < 4; ++rg) {
        float v = acc[i][j][rg] + bias[j];
        int row16 = fq * 4 + rg;
        int off = w * 4096 + row16 * 256 + (j * 16 + fr) * 4;
        off ^= (row16 & 1) << 6;
        *(float*)(smem + off) = v > 0.f ? v : 0.f;
      }
    __syncthreads();
    int R = wm * 64 + i * 16 + lr;
    if (R < ce_cnt - rs) {
      float* orow = out + (size_t)toks[R] * HID + nx * 128 + wn * 64;
#pragma unroll
      for (int s = 0; s < 4; ++s) {
        int ch = (lane & 3) + s * 4;
        int off = w * 4096 + lr * 256 + ch * 16;
        off ^= (lr & 1) << 6;
        *(float4*)(orow + ch * 4) = *(const float4*)(smem + off);
      }
    }
  }
}

// ---------------- workspace layout (bytes) ----------------
// cnt     @ 0          (512)          — zeroed (with ce) by one memset
// ce      @ 512        (32768)        -> 33280
// idx     @ 36864      (524288)       -> 561152
// W1p     @ 561152     (16777216)     -> 17338368
// W2p     @ 17338368   (16777216)     -> 34115584
// hp      @ 34115584   (35651584)     -> 69767168
// xb      @ 69767168   (33554432)     -> 103321600 (~103.3 MB)

extern "C" void kernel_launch(void* const* d_in, const int* in_sizes, int n_in,
                              void* d_out, int out_size, void* d_ws, size_t ws_size,
                              hipStream_t stream) {
  const float* x   = (const float*)d_in[0];
  const int*   ops = (const int*)d_in[1];
  const float* emb = (const float*)d_in[2];
  const float* W1  = (const float*)d_in[3];
  const float* b1  = (const float*)d_in[4];
  const float* W2  = (const float*)d_in[5];
  const float* b2  = (const float*)d_in[6];
  float* out = (float*)d_out;

  char* ws = (char*)d_ws;
  int* cnt  = (int*)(ws + 0);
  float* ce = (float*)(ws + 512);
  int* idx  = (int*)(ws + 36864);
  short* W1p = (short*)(ws + 561152);
  short* W2p = (short*)(ws + 17338368);
  unsigned short* hp = (unsigned short*)(ws + 34115584);
  unsigned int* xb = (unsigned int*)(ws + 69767168);

  hipMemsetAsync(ws, 0, 33280, stream);   // cnt + ce
  bucket_ce_k<<<2240 + 4096, 256, 0, stream>>>(ops, cnt, idx, W1, emb, b1, ce, W1p, x, xb);
  gemm1_w2_k<<<8 * MAXT + 2048, 256, 0, stream>>>(xb, idx, ce, W1p, hp, cnt, W2, W2p);
  gemm2_k<<<8 * MAXT, 256, 0, stream>>>(hp, b2, W2p, out, idx, cnt);
}

// Round 8
// 274.407 us; speedup vs baseline: 1.1190x; 1.0759x over previous
//
#include <hip/hip_runtime.h>
#include <hip/hip_bf16.h>

#define BATCH 16384
#define HID   1024
#define EMBD  512
#define NOPS  8
#define MAXT  136   // max tile slots: sum ceil(cnt_e/128) <= 135
#define CNTS  16    // cnt stride in ints (64 B) — one cache line per expert

typedef __attribute__((ext_vector_type(8))) short bf16x8;
typedef __attribute__((ext_vector_type(4))) float f32x4;

#define VMWAIT(N) asm volatile("s_waitcnt vmcnt(" #N ")" ::: "memory")
// raw s_barrier is NO-MEM to LLVM IR (that's why __syncthreads wraps it in
// fences) and sched_barrier(0) only constrains the MIR scheduler — IR passes
// can hoist LDS reads / global_load_lds issues above the barrier (round-6
// absmax fail). Empty asm with "memory" clobber = zero-inst compiler fence.
#define BARRIER_FENCED()                      \
  do {                                        \
    asm volatile("" ::: "memory");            \
    __builtin_amdgcn_s_barrier();             \
    asm volatile("" ::: "memory");            \
    __builtin_amdgcn_sched_barrier(0);        \
  } while (0)

__device__ __forceinline__ unsigned short f2bf(float f) {
  unsigned int u = __float_as_uint(f);
  u += 0x7FFF + ((u >> 16) & 1);
  return (unsigned short)(u >> 16);
}

__device__ __forceinline__ unsigned int pk2(float a, float b) {
  __hip_bfloat162 t = __float22bfloat162_rn(make_float2(a, b));
  return *(unsigned int*)(&t);
}

__device__ __forceinline__ void lds_load16(void* lds, const void* g) {
  __builtin_amdgcn_global_load_lds(
      (const __attribute__((address_space(1))) unsigned int*)g,
      (__attribute__((address_space(3))) unsigned int*)lds, 16, 0, 0);
}

// XCD-locality decode: linear blocks round-robin across 8 XCDs, so bid&7 is
// the XCD. All 8 nx-blocks of a g land on one XCD (A-slab L2 reuse), and each
// XCD covers contiguous g-range [17c, 17c+17) ~= one expert (W-slab in L2).
__device__ __forceinline__ void decode_bid(int bid, int& g, int& nx) {
  g = 17 * (bid & 7) + (bid >> 6);
  nx = (bid >> 3) & 7;
}

// schedule_k replacement: each block derives (e, rs) for its tile g from the
// 8 cnt values with a scalar prefix scan (uniform -> SGPR). Returns -1 if
// g >= total tile count.
__device__ __forceinline__ int decode_tile(const int* __restrict__ cnt,
                                           int g, int& rs, int& ce_cnt) {
  int e = -1, at = 0;
  rs = 0; ce_cnt = 0;
#pragma unroll
  for (int o = 0; o < NOPS; ++o) {
    int c = cnt[o * CNTS];
    int t = (c + 127) >> 7;
    if (e < 0 && g < at + t) { e = o; rs = (g - at) * 128; ce_cnt = c; }
    at += t;
  }
  return e;
}

// LDS-free weight transpose tile, fq-major slab layout:
//   slab[kq][n][kk] bf16 (kq=k/8 in 0..3, n in 0..127, kk=k%8)
//   value = W[ks*32 + kq*8 + kk][nx*128 + n]
// Fragment ds_read (fq*128+row)*16B: consecutive 8 lanes cover a full 128B
// stripe -> conflict-free.
__device__ __forceinline__ void w_prep_tile(const float* __restrict__ W,
                                            short* __restrict__ Wp,
                                            int ks, int nx, int tid) {
  int n = tid & 127, kh = tid >> 7;           // kh: low/high 16 of the 32-k tile
  const float* src = W + (size_t)(ks * 32 + kh * 16) * 1024 + nx * 128 + n;
  float v[16];
#pragma unroll
  for (int kk = 0; kk < 16; ++kk) v[kk] = src[(size_t)kk * 1024];
  uint4 a, b;
  a.x = pk2(v[0], v[1]);  a.y = pk2(v[2], v[3]);
  a.z = pk2(v[4], v[5]);  a.w = pk2(v[6], v[7]);
  b.x = pk2(v[8], v[9]);  b.y = pk2(v[10], v[11]);
  b.z = pk2(v[12], v[13]); b.w = pk2(v[14], v[15]);
  uint4* dst = (uint4*)Wp;
  dst[(2 * kh) * 128 + n]     = a;            // kq = 2*kh   (k 0..7 of this half)
  dst[(2 * kh + 1) * 128 + n] = b;            // kq = 2*kh+1 (k 8..15)
}

// ---- phase 0: bucket (64) + ce (128) + W1 prep (2048) + xb convert (4096) ---
// xb = bf16(x) in token order — bucket-independent, so it rides in phase 0.
// gemm1 then gathers A rows straight from xb via per-lane global_load_lds.
// ce[e][n] = b1[e][n] + sum_k emb[e][k] * W1[e][1024+k][n] — embedding half of
// GEMM1 collapses to a per-(expert,n) constant, cutting GEMM1 K 1536 -> 1024.
__global__ void bucket_ce_k(const int* __restrict__ ops, int* __restrict__ cnt,
                            int* __restrict__ idx, const float* __restrict__ W1,
                            const float* __restrict__ emb,
                            const float* __restrict__ b1, float* __restrict__ ce,
                            short* __restrict__ W1p, const float* __restrict__ x,
                            unsigned int* __restrict__ xb) {
  int bid = blockIdx.x;
  int tid = threadIdx.x;
  if (bid >= 2240) {
    // ---- xb path: f32 -> bf16, 4096 blocks * 4096 elems ----
    size_t i = ((size_t)(bid - 2240) * 256 + tid) * 16;
    const float4* src = (const float4*)(x + i);
    float4 f0 = src[0], f1 = src[1], f2v = src[2], f3 = src[3];
    uint4 p0 = make_uint4(pk2(f0.x, f0.y), pk2(f0.z, f0.w),
                          pk2(f1.x, f1.y), pk2(f1.z, f1.w));
    uint4 p1 = make_uint4(pk2(f2v.x, f2v.y), pk2(f2v.z, f2v.w),
                          pk2(f3.x, f3.y), pk2(f3.z, f3.w));
    uint4* dst = (uint4*)(xb + i / 2);
    dst[0] = p0;
    dst[1] = p1;
    return;
  }
  if (bid >= 192) {
    // ---- W1 path: 8 e * 8 nx * 32 ks (first 1024 rows only) ----
    int b = bid - 192;
    int e = b / 256; int rr = b % 256; int nx = rr / 32, ks = rr % 32;
    w_prep_tile(W1 + (size_t)e * 1536 * 1024,
                W1p + ((size_t)(e * 8 + nx) * 32 + ks) * 4096, ks, nx, tid);
    return;
  }
  if (bid >= 64) {
    // ---- ce path ----
    int cb = bid - 64;
    int e = cb >> 4, kp = cb & 15;
    int n = tid * 4;
    const float* Wc = W1 + (size_t)e * 1536 * 1024 + (size_t)(1024 + kp * 32) * 1024 + n;
    const float* ee = emb + e * EMBD + kp * 32;
    float4 a = make_float4(0.f, 0.f, 0.f, 0.f);
#pragma unroll
    for (int kk = 0; kk < 32; ++kk) {
      float s = ee[kk];
      float4 r = *(const float4*)(Wc + (size_t)kk * 1024);
      a.x += s * r.x; a.y += s * r.y; a.z += s * r.z; a.w += s * r.w;
    }
    if (kp == 0) {
      float4 b = *(const float4*)(b1 + e * HID + n);
      a.x += b.x; a.y += b.y; a.z += b.z; a.w += b.w;
    }
    float* d = ce + e * HID + n;
    atomicAdd(d + 0, a.x); atomicAdd(d + 1, a.y);
    atomicAdd(d + 2, a.z); atomicAdd(d + 3, a.w);
    return;
  }
  // ---- bucket path (block-aggregated atomics) ----
  __shared__ int wcnt[4][NOPS];
  __shared__ int wbase[4][NOPS];
  int lane = tid & 63, w = tid >> 6;
  int t = bid * 256 + tid;
  int op = ops[t];
  unsigned long long msave = 0;
#pragma unroll
  for (int o = 0; o < NOPS; ++o) {
    unsigned long long mm = __ballot(op == o);
    if (op == o) msave = mm;
    if (lane == o) wcnt[w][o] = __popcll(mm);
  }
  __syncthreads();
  if (tid < NOPS) {
    int c0 = wcnt[0][tid], c1 = wcnt[1][tid], c2 = wcnt[2][tid], c3 = wcnt[3][tid];
    int base = atomicAdd(&cnt[tid * CNTS], c0 + c1 + c2 + c3);
    wbase[0][tid] = base;
    wbase[1][tid] = base + c0;
    wbase[2][tid] = base + c0 + c1;
    wbase[3][tid] = base + c0 + c1 + c2;
  }
  __syncthreads();
  int pre = __popcll(msave & ((1ull << lane) - 1ull));
  idx[op * BATCH + wbase[w][op] + pre] = t;
}

// ---------------- phase 1: GEMM1 gathered-DMA A (1088) + W2 prep (2048) ------
// h = relu(x_tile @ W1[e][:1024] + ce[e]); K = 1024 (32 iters).
// LINE-MERGED A-gather (round-8 fix): 4 consecutive lanes fetch the 4 16B
// quarters of ONE token row's 64B ks-slice -> same-line requests merge into 1
// L2 transaction per row (old mapping: 64 lanes -> 64 distinct lines/instr;
// A tx 512 -> 128 per block-ks; pipelining couldn't hide this THROUGHPUT
// limit, which is why rounds 3-7 scheduling moved nothing at MfmaUtil 18%).
// The linear LDS dest then gives row-major A [128 r][32 k]; the k-quarter is
// XOR-swizzled by (row>>1)&3 on the per-lane SOURCE address (rule #21) so
// fragment ds_reads stay conflict-free: every consecutive-8-lane group covers
// all 8 16B slots of a 128B stripe.
__global__ __launch_bounds__(256, 3) void gemm1_w2_k(
    const unsigned int* __restrict__ xb, const int* __restrict__ idx,
    const float* __restrict__ ce, const short* __restrict__ W1p,
    unsigned short* __restrict__ hp, const int* __restrict__ cnt,
    const float* __restrict__ W2, short* __restrict__ W2p) {
  int bid = blockIdx.x;
  int tid = threadIdx.x;
  if (bid >= 8 * MAXT) {
    // ---- W2 path: 8 e * 8 nx * 32 ks ----
    int b = bid - 8 * MAXT;
    int e = b / 256; int rr = b % 256; int nx = rr / 32, ks = rr % 32;
    w_prep_tile(W2 + (size_t)e * 1024 * 1024,
                W2p + ((size_t)(e * 8 + nx) * 32 + ks) * 4096, ks, nx, tid);
    return;
  }
  int g, nx;
  decode_bid(bid, g, nx);
  int rs, ce_cnt;
  int e = decode_tile(cnt, g, rs, ce_cnt);
  if (e < 0) return;

  __shared__ __align__(16) char smem[49152];   // 3 x (8KB A + 8KB B)
  char* s0 = smem;
  char* s1 = smem + 16384;
  char* s2 = smem + 32768;

  int lane = tid & 63, w = tid >> 6;
  int wm = w >> 1, wn = w & 1;
  int fr = lane & 15, fq = lane >> 4;

  // A-gather roles: wave w stages rows w*32 .. w*32+31 (2 instrs of 16 rows).
  // lane -> (row_local = lane>>2, phys quarter = lane&3); source k-quarter is
  // XOR-swizzled: q_src = (lane&3) ^ ((lane>>3)&3)  [= phys ^ ((row>>1)&3)].
  int r0 = w * 32 + (lane >> 2);
  int r1 = r0 + 16;
  int qs = (lane & 3) ^ ((lane >> 3) & 3);
  int pp0 = rs + r0, pp1 = rs + r1;
  int t0 = (pp0 < ce_cnt) ? idx[e * BATCH + pp0] : 0;
  int t1 = (pp1 < ce_cnt) ? idx[e * BATCH + pp1] : 0;
  const char* pa0 = (const char*)xb + (size_t)t0 * 2048 + qs * 16;
  const char* pa1 = (const char*)xb + (size_t)t1 * 2048 + qs * 16;
  const char* pb0 = (const char*)W1p + (size_t)(e * 8 + nx) * 32 * 8192
                    + w * 1024 + lane * 16;
  const char* pb1 = pb0 + 4096;

#define G1_STAGE(NB)                                                          \
  {                                                                           \
    lds_load16((NB) + w * 2048,         pa0);                                 \
    lds_load16((NB) + w * 2048 + 1024,  pa1);                                 \
    lds_load16((NB) + 8192 + w * 1024,  pb0);                                 \
    lds_load16((NB) + 12288 + w * 1024, pb1);                                 \
    pa0 += 64; pa1 += 64; pb0 += 8192; pb1 += 8192;                           \
  }

#define G1_COMP(CB)                                                           \
  {                                                                           \
    const short* lA_ = (const short*)(CB);                                    \
    const short* lB_ = (const short*)((CB) + 8192);                           \
    bf16x8 af[4], bfr[4];                                                     \
    _Pragma("unroll")                                                         \
    for (int i = 0; i < 4; ++i) af[i] = *(const bf16x8*)&lA_[fo + i * 512];   \
    _Pragma("unroll")                                                         \
    for (int j = 0; j < 4; ++j) bfr[j] = *(const bf16x8*)&lB_[bo + j * 128];  \
    _Pragma("unroll")                                                         \
    for (int i = 0; i < 4; ++i)                                               \
      _Pragma("unroll")                                                       \
      for (int j = 0; j < 4; ++j)                                             \
        acc[i][j] = __builtin_amdgcn_mfma_f32_16x16x32_bf16(af[i], bfr[j],    \
                                                            acc[i][j], 0, 0, 0); \
  }

#define G1_STEP(CB, NB)                                                       \
  {                                                                           \
    G1_STAGE(NB);                                                             \
    G1_COMP(CB);                                                              \
    VMWAIT(4);                                                                \
    BARRIER_FENCED();                                                         \
  }

  // prologue: stage ks=0 -> s0, ks=1 -> s1; wait for s0 only (4 in flight)
  G1_STAGE(s0);
  G1_STAGE(s1);
  VMWAIT(4);
  BARRIER_FENCED();

  f32x4 acc[4][4] = {};
  // A frag (row-major + quarter swizzle): row = wm*64+i*16+fr, phys quarter
  // q' = fq ^ ((fr>>1)&3)  [(row>>1)&3 == (fr>>1)&3 since wm*64,i*16 ≡ 0 mod 8]
  int fo = (wm * 64 + fr) * 32 + (fq ^ ((fr >> 1) & 3)) * 8;  // shorts, +i*512
  int bo = (fq * 128 + wn * 64 + fr) * 8;                     // B-frag base

  for (int it = 0; it < 10; ++it) {         // ks = 0..29
    G1_STEP(s0, s2);
    G1_STEP(s1, s0);
    G1_STEP(s2, s1);
  }
  // ks = 30: nothing left to stage; need ks=31's loads (into s1) complete
  G1_COMP(s0);
  VMWAIT(0);
  BARRIER_FENCED();
  // ks = 31
  G1_COMP(s1);

#undef G1_STEP
#undef G1_COMP
#undef G1_STAGE

  // epilogue: +ce (bias incl. embedding term) + relu + bf16, coalesced via LDS.
  // hp layout (fq-major): [g][ks2(32)][kq(4)][128 r][8 k] — gemm2 staging is a
  // linear 8 KB slab copy. LDS round-trip gets a 1-bit XOR swizzle.
  float bias[4];
#pragma unroll
  for (int j = 0; j < 4; ++j)
    bias[j] = ce[e * HID + nx * 128 + wn * 64 + j * 16 + fr];

  int lr = lane >> 2;
#pragma unroll
  for (int i = 0; i < 4; ++i) {
    __syncthreads();
#pragma unroll
    for (int j = 0; j < 4; ++j)
#pragma unroll
      for (int rg = 0; rg < 4; ++rg) {
        float v = acc[i][j][rg] + bias[j];
        v = v > 0.f ? v : 0.f;
        int row16 = fq * 4 + rg;
        int off = w * 2048 + row16 * 128 + (j * 16 + fr) * 2;
        off ^= (row16 & 1) << 6;
        *(unsigned short*)(smem + off) = f2bf(v);
      }
    __syncthreads();
    int R = wm * 64 + i * 16 + lr;
#pragma unroll
    for (int s = 0; s < 2; ++s) {
      int ch = (lane & 3) + s * 4;
      int off = w * 2048 + lr * 128 + ch * 16;
      off ^= (lr & 1) << 6;
      uint4 val = *(const uint4*)(smem + off);
      int ks2 = nx * 4 + wn * 2 + (ch >> 2);
      int kq = ch & 3;
      *(uint4*)(hp + (((size_t)(g * 32 + ks2) * 4 + kq) * 128 + R) * 8) = val;
    }
  }
}

// ---------------- phase 2: GEMM2  out[tok] = relu(h @ W2[e] + b2[e]) ---------
__global__ __launch_bounds__(256, 3) void gemm2_k(
    const unsigned short* __restrict__ hp, const float* __restrict__ b2,
    const short* __restrict__ W2p, float* __restrict__ out,
    const int* __restrict__ idx, const int* __restrict__ cnt) {
  int g, nx;
  decode_bid(blockIdx.x, g, nx);
  int rs, ce_cnt;
  int e = decode_tile(cnt, g, rs, ce_cnt);
  if (e < 0) return;

  __shared__ __align__(16) char smem[49152];   // 3 x (8KB A + 8KB B)
  __shared__ int toks[128];
  char* s0 = smem;
  char* s1 = smem + 16384;
  char* s2 = smem + 32768;

  int tid = threadIdx.x, lane = tid & 63, w = tid >> 6;
  int wm = w >> 1, wn = w & 1;
  int fr = lane & 15, fq = lane >> 4;

  if (tid < 128) {
    int p = rs + tid;
    toks[tid] = (p < ce_cnt) ? idx[e * BATCH + p] : 0;
  }

  const char* Asrc = (const char*)hp + (size_t)g * 32 * 8192;
  const char* Bsrc = (const char*)W2p + (size_t)(e * 8 + nx) * 32 * 8192;
  const char* pA0 = Asrc + w * 1024 + lane * 16;
  const char* pA1 = pA0 + 4096;
  const char* pB0 = Bsrc + w * 1024 + lane * 16;
  const char* pB1 = pB0 + 4096;

#define G2_STAGE(NB)                                                          \
  {                                                                           \
    lds_load16((NB) + w * 1024,         pA0);                                 \
    lds_load16((NB) + 4096 + w * 1024,  pA1);                                 \
    lds_load16((NB) + 8192 + w * 1024,  pB0);                                 \
    lds_load16((NB) + 12288 + w * 1024, pB1);                                 \
    pA0 += 8192; pA1 += 8192; pB0 += 8192; pB1 += 8192;                       \
  }

#define G2_COMP(CB)                                                           \
  {                                                                           \
    const short* lA_ = (const short*)(CB);                                    \
    const short* lB_ = (const short*)((CB) + 8192);                           \
    bf16x8 af[4], bfr[4];                                                     \
    _Pragma("unroll")                                                         \
    for (int i = 0; i < 4; ++i) af[i] = *(const bf16x8*)&lA_[fo + i * 128];   \
    _Pragma("unroll")                                                         \
    for (int j = 0; j < 4; ++j) bfr[j] = *(const bf16x8*)&lB_[bo + j * 128];  \
    _Pragma("unroll")                                                         \
    for (int i = 0; i < 4; ++i)                                               \
      _Pragma("unroll")                                                       \
      for (int j = 0; j < 4; ++j)                                             \
        acc[i][j] = __builtin_amdgcn_mfma_f32_16x16x32_bf16(af[i], bfr[j],    \
                                                            acc[i][j], 0, 0, 0); \
  }

#define G2_STEP(CB, NB)                                                       \
  {                                                                           \
    G2_STAGE(NB);                                                             \
    G2_COMP(CB);                                                              \
    VMWAIT(4);                                                                \
    BARRIER_FENCED();                                                         \
  }

  // prologue: stage ks=0 -> s0, ks=1 -> s1
  G2_STAGE(s0);
  G2_STAGE(s1);
  VMWAIT(4);
  BARRIER_FENCED();

  f32x4 acc[4][4] = {};
  int fo = (fq * 128 + wm * 64 + fr) * 8;
  int bo = (fq * 128 + wn * 64 + fr) * 8;

  for (int it = 0; it < 10; ++it) {         // ks = 0..29
    G2_STEP(s0, s2);
    G2_STEP(s1, s0);
    G2_STEP(s2, s1);
  }
  G2_COMP(s0);          // ks = 30
  VMWAIT(0);
  BARRIER_FENCED();
  G2_COMP(s1);          // ks = 31

#undef G2_STEP
#undef G2_COMP
#undef G2_STAGE

  // epilogue: bias + relu + scatter to out rows, coalesced via LDS round-trip.
  float bias[4];
#pragma unroll
  for (int j = 0; j < 4; ++j)
    bias[j] = b2[e * HID + nx * 128 + wn * 64 + j * 16 + fr];

  int lr = lane >> 2;
#pragma unroll
  for (int i = 0; i < 4; ++i) {
    __syncthreads();
#pragma unroll
    for (int j = 0; j < 4; ++j)
#pragma unroll
      for (int rg = 0; rg < 4; ++rg) {
        float v = acc[i][j][rg] + bias[j];
        int row16 = fq * 4 + rg;
        int off = w * 4096 + row16 * 256 + (j * 16 + fr) * 4;
        off ^= (row16 & 1) << 6;
        *(float*)(smem + off) = v > 0.f ? v : 0.f;
      }
    __syncthreads();
    int R = wm * 64 + i * 16 + lr;
    if (R < ce_cnt - rs) {
      float* orow = out + (size_t)toks[R] * HID + nx * 128 + wn * 64;
#pragma unroll
      for (int s = 0; s < 4; ++s) {
        int ch = (lane & 3) + s * 4;
        int off = w * 4096 + lr * 256 + ch * 16;
        off ^= (lr & 1) << 6;
        *(float4*)(orow + ch * 4) = *(const float4*)(smem + off);
      }
    }
  }
}

// ---------------- workspace layout (bytes) ----------------
// cnt     @ 0          (512)          — zeroed (with ce) by one memset
// ce      @ 512        (32768)        -> 33280
// idx     @ 36864      (524288)       -> 561152
// W1p     @ 561152     (16777216)     -> 17338368
// W2p     @ 17338368   (16777216)     -> 34115584
// hp      @ 34115584   (35651584)     -> 69767168
// xb      @ 69767168   (33554432)     -> 103321600 (~103.3 MB)

extern "C" void kernel_launch(void* const* d_in, const int* in_sizes, int n_in,
                              void* d_out, int out_size, void* d_ws, size_t ws_size,
                              hipStream_t stream) {
  const float* x   = (const float*)d_in[0];
  const int*   ops = (const int*)d_in[1];
  const float* emb = (const float*)d_in[2];
  const float* W1  = (const float*)d_in[3];
  const float* b1  = (const float*)d_in[4];
  const float* W2  = (const float*)d_in[5];
  const float* b2  = (const float*)d_in[6];
  float* out = (float*)d_out;

  char* ws = (char*)d_ws;
  int* cnt  = (int*)(ws + 0);
  float* ce = (float*)(ws + 512);
  int* idx  = (int*)(ws + 36864);
  short* W1p = (short*)(ws + 561152);
  short* W2p = (short*)(ws + 17338368);
  unsigned short* hp = (unsigned short*)(ws + 34115584);
  unsigned int* xb = (unsigned int*)(ws + 69767168);

  hipMemsetAsync(ws, 0, 33280, stream);   // cnt + ce
  bucket_ce_k<<<2240 + 4096, 256, 0, stream>>>(ops, cnt, idx, W1, emb, b1, ce, W1p, x, xb);
  gemm1_w2_k<<<8 * MAXT + 2048, 256, 0, stream>>>(xb, idx, ce, W1p, hp, cnt, W2, W2p);
  gemm2_k<<<8 * MAXT, 256, 0, stream>>>(hp, b2, W2p, out, idx, cnt);
}